// Round 1
// baseline (773.993 us; speedup 1.0000x reference)
//
#include <hip/hip_runtime.h>
#include <math.h>

#define BB 4
#define CIN 128
#define LL 2048
#define HH 8
#define CH 32
#define HID 256

__device__ __forceinline__ float dot4(float4 a, float4 b) {
    return a.x*b.x + a.y*b.y + a.z*b.z + a.w*b.w;
}

// ---------------------------------------------------------------------------
// Kernel 1: QKV 1x1 conv.  qkv[b,o,l] = sum_i w[o,i] x[b,i,l] + b[o]
// o = sel*256 + h*32 + c.  Store as q/k/v[bh][l][c] (c fast), q pre-scaled by 1/sqrt(L).
// Block: (b, sel*8+h, l-tile of 64). 256 threads.
// ---------------------------------------------------------------------------
__global__ __launch_bounds__(256) void qkv_kernel(
        const float* __restrict__ x, const float* __restrict__ w_qkv,
        const float* __restrict__ b_qkv,
        float* __restrict__ q_ws, float* __restrict__ k_ws, float* __restrict__ v_ws) {
    __shared__ float wl[32 * 128];   // 16 KB weight tile
    __shared__ float tr[32 * 65];    // transpose buffer (padded)
    const int t = threadIdx.x;
    const int lt = blockIdx.x;           // 0..31
    const int g  = blockIdx.y;           // 0..23 : sel*8 + h
    const int b  = blockIdx.z;
    const int sel = g >> 3, h = g & 7;
    const int obase = sel * 256 + h * 32;
    const int l0 = lt * 64;

    const float4* wsrc = (const float4*)(w_qkv + (size_t)obase * CIN);
    float4* wdst = (float4*)wl;
    #pragma unroll
    for (int r = 0; r < 4; ++r) wdst[r * 256 + t] = wsrc[r * 256 + t];
    __syncthreads();

    const int ll = t & 63, og = t >> 6;
    float acc[8] = {0.f,0.f,0.f,0.f,0.f,0.f,0.f,0.f};
    const float* xp = x + (size_t)b * CIN * LL + l0 + ll;
    for (int i = 0; i < CIN; i += 4) {
        float x0 = xp[(size_t)(i+0) * LL];
        float x1 = xp[(size_t)(i+1) * LL];
        float x2 = xp[(size_t)(i+2) * LL];
        float x3 = xp[(size_t)(i+3) * LL];
        #pragma unroll
        for (int j = 0; j < 8; ++j) {
            float4 w4 = *(const float4*)(wl + (og * 8 + j) * 128 + i);
            acc[j] += w4.x * x0 + w4.y * x1 + w4.z * x2 + w4.w * x3;
        }
    }
    const float scale = (sel == 0) ? 0.02209708691207961f : 1.0f;  // 1/sqrt(2048)
    #pragma unroll
    for (int j = 0; j < 8; ++j) {
        int oc = og * 8 + j;
        tr[oc * 65 + ll] = (acc[j] + b_qkv[obase + oc]) * scale;
    }
    __syncthreads();
    float* dst = (sel == 0 ? q_ws : (sel == 1 ? k_ws : v_ws))
                 + ((size_t)(b * HH + h) * LL + l0) * CH;
    #pragma unroll
    for (int r = 0; r < 8; ++r) {
        int flat = r * 256 + t;          // = lr*32 + c
        int c = flat & 31, lr = flat >> 5;
        dst[flat] = tr[c * 65 + lr];
    }
}

// ---------------------------------------------------------------------------
// Kernel 2: softmax denominators. invz[bh][q] = 1 / sum_a exp(q . k_a)
// Block: (q-tile of 64, bh). 256 threads: lane = q row, 4 groups over a.
// ---------------------------------------------------------------------------
__global__ __launch_bounds__(256) void denom_kernel(
        const float* __restrict__ q_ws, const float* __restrict__ k_ws,
        float* __restrict__ invz) {
    __shared__ float kl[64 * 32];
    __shared__ float zbuf[4 * 64];
    const int t = threadIdx.x;
    const int qt = blockIdx.x;   // 0..31
    const int bh = blockIdx.y;   // 0..31
    const int lane = t & 63, g = t >> 6;

    float4 qr[8];
    const float4* qsrc = (const float4*)(q_ws + ((size_t)bh * LL + qt * 64 + lane) * CH);
    #pragma unroll
    for (int c4 = 0; c4 < 8; ++c4) qr[c4] = qsrc[c4];

    float z = 0.f;
    for (int at = 0; at < 32; ++at) {
        __syncthreads();
        const float4* ks = (const float4*)(k_ws + ((size_t)bh * LL + at * 64) * CH);
        float4* kd = (float4*)kl;
        kd[t] = ks[t];
        kd[256 + t] = ks[256 + t];
        __syncthreads();
        #pragma unroll 4
        for (int j = 0; j < 16; ++j) {
            const float4* kr = (const float4*)(kl + (g * 16 + j) * 32);
            float s = 0.f;
            #pragma unroll
            for (int c4 = 0; c4 < 8; ++c4) s += dot4(qr[c4], kr[c4]);
            z += __expf(s);
        }
    }
    zbuf[g * 64 + lane] = z;
    __syncthreads();
    if (t < 64) {
        float zz = zbuf[t] + zbuf[64 + t] + zbuf[128 + t] + zbuf[192 + t];
        invz[(size_t)bh * LL + qt * 64 + t] = 1.0f / zz;
    }
}

// ---------------------------------------------------------------------------
// Kernel 3: attn^T[b, h*32+d, a] = sum_q exp(s[q,a]) * invz[q] * v[q,d]
// Block: (a-tile of 64, bh). lane = a row (K row in regs); group g owns
// q rows g*16..g*16+15 and keeps partial acc[32] (all d) in registers;
// cross-group reduce via LDS at the end.
// ---------------------------------------------------------------------------
__global__ __launch_bounds__(256) void attn_kernel(
        const float* __restrict__ q_ws, const float* __restrict__ k_ws,
        const float* __restrict__ v_ws, const float* __restrict__ invz,
        float* __restrict__ attnT) {
    __shared__ float ql[64 * 32];
    __shared__ float vl[64 * 32];
    __shared__ float zl[64];
    __shared__ float red[2 * 64 * 33];   // padded reduce buffer
    const int t = threadIdx.x;
    const int at = blockIdx.x;   // 0..31
    const int bh = blockIdx.y;   // 0..31
    const int lane = t & 63, g = t >> 6;

    float4 kr[8];
    const float4* ksrc = (const float4*)(k_ws + ((size_t)bh * LL + at * 64 + lane) * CH);
    #pragma unroll
    for (int c4 = 0; c4 < 8; ++c4) kr[c4] = ksrc[c4];

    float acc[32];
    #pragma unroll
    for (int d = 0; d < 32; ++d) acc[d] = 0.f;

    for (int qt = 0; qt < 32; ++qt) {
        __syncthreads();
        const float4* qs = (const float4*)(q_ws + ((size_t)bh * LL + qt * 64) * CH);
        const float4* vs = (const float4*)(v_ws + ((size_t)bh * LL + qt * 64) * CH);
        ((float4*)ql)[t]       = qs[t];
        ((float4*)ql)[256 + t] = qs[256 + t];
        ((float4*)vl)[t]       = vs[t];
        ((float4*)vl)[256 + t] = vs[256 + t];
        if (t < 64) zl[t] = invz[(size_t)bh * LL + qt * 64 + t];
        __syncthreads();
        #pragma unroll 2
        for (int j = 0; j < 16; ++j) {
            const int qrow = g * 16 + j;
            const float4* qq = (const float4*)(ql + qrow * 32);
            float s = 0.f;
            #pragma unroll
            for (int c4 = 0; c4 < 8; ++c4) s += dot4(kr[c4], qq[c4]);
            const float w = __expf(s) * zl[qrow];
            const float4* vv = (const float4*)(vl + qrow * 32);
            #pragma unroll
            for (int c4 = 0; c4 < 8; ++c4) {
                float4 v4 = vv[c4];
                acc[c4*4+0] += w * v4.x;
                acc[c4*4+1] += w * v4.y;
                acc[c4*4+2] += w * v4.z;
                acc[c4*4+3] += w * v4.w;
            }
        }
    }

    // cross-group reduction: attn[a][d] = sum_g acc_g[a][d]
    __syncthreads();
    if (g >= 2) {
        #pragma unroll
        for (int d = 0; d < 32; ++d) red[(g - 2) * 64 * 33 + lane * 33 + d] = acc[d];
    }
    __syncthreads();
    if (g < 2) {
        #pragma unroll
        for (int d = 0; d < 32; ++d) acc[d] += red[g * 64 * 33 + lane * 33 + d];
    }
    __syncthreads();
    if (g == 1) {
        #pragma unroll
        for (int d = 0; d < 32; ++d) red[lane * 33 + d] = acc[d];
    }
    __syncthreads();
    if (g == 0) {
        const int b = bh >> 3, h = bh & 7;
        #pragma unroll
        for (int d = 0; d < 32; ++d) {
            float v = acc[d] + red[lane * 33 + d];
            attnT[((size_t)b * HID + h * CH + d) * LL + at * 64 + lane] = v;
        }
    }
}

// ---------------------------------------------------------------------------
// Kernel 4: out[b,o,l] = BN( w_out @ attnT + b_out + x )
// Block: (l-tile 256, o-tile 16, b). 256 threads = l.
// ---------------------------------------------------------------------------
__global__ __launch_bounds__(256) void out_kernel(
        const float* __restrict__ attnT, const float* __restrict__ x,
        const float* __restrict__ w_out, const float* __restrict__ b_out,
        const float* __restrict__ bnw, const float* __restrict__ bnb,
        const float* __restrict__ bnm, const float* __restrict__ bnv,
        float* __restrict__ out) {
    __shared__ float wl[16 * 256];
    const int t = threadIdx.x;
    const int l0 = blockIdx.x * 256;
    const int o0 = blockIdx.y * 16;
    const int b  = blockIdx.z;

    const float4* ws = (const float4*)(w_out + (size_t)o0 * HID);
    float4* wd = (float4*)wl;
    #pragma unroll
    for (int r = 0; r < 4; ++r) wd[r * 256 + t] = ws[r * 256 + t];
    __syncthreads();

    float acc[16];
    #pragma unroll
    for (int j = 0; j < 16; ++j) acc[j] = 0.f;
    const float* ap = attnT + (size_t)b * HID * LL + l0 + t;
    for (int i = 0; i < HID; i += 4) {
        float a0 = ap[(size_t)(i+0) * LL];
        float a1 = ap[(size_t)(i+1) * LL];
        float a2 = ap[(size_t)(i+2) * LL];
        float a3 = ap[(size_t)(i+3) * LL];
        #pragma unroll
        for (int j = 0; j < 16; ++j) {
            float4 w4 = *(const float4*)(wl + j * 256 + i);
            acc[j] += w4.x * a0 + w4.y * a1 + w4.z * a2 + w4.w * a3;
        }
    }
    #pragma unroll
    for (int j = 0; j < 16; ++j) {
        const int o = o0 + j;
        const float inv = bnw[o] / sqrtf(bnv[o] + 1e-5f);
        const float sh  = bnb[o] - bnm[o] * inv;
        const size_t idx = ((size_t)b * CIN + o) * LL + l0 + t;
        float val = acc[j] + b_out[o] + x[idx];
        out[idx] = val * inv + sh;
    }
}

// ---------------------------------------------------------------------------
extern "C" void kernel_launch(void* const* d_in, const int* in_sizes, int n_in,
                              void* d_out, int out_size, void* d_ws, size_t ws_size,
                              hipStream_t stream) {
    const float* x      = (const float*)d_in[0];
    const float* w_qkv  = (const float*)d_in[1];
    const float* b_qkv  = (const float*)d_in[2];
    const float* w_out  = (const float*)d_in[3];
    const float* b_out  = (const float*)d_in[4];
    const float* bnw    = (const float*)d_in[5];
    const float* bnb    = (const float*)d_in[6];
    const float* bnm    = (const float*)d_in[7];
    const float* bnv    = (const float*)d_in[8];
    float* out = (float*)d_out;

    // workspace layout (floats)
    const size_t QKV_ELEMS = (size_t)BB * HH * LL * CH;  // 2,097,152
    float* f = (float*)d_ws;
    float* q_ws  = f;
    float* k_ws  = f + QKV_ELEMS;
    float* v_ws  = f + 2 * QKV_ELEMS;
    float* invz  = f + 3 * QKV_ELEMS;                    // B*H*L = 65,536
    float* attnT = f + 3 * QKV_ELEMS + (size_t)BB * HH * LL;  // B*256*L

    qkv_kernel<<<dim3(32, 24, BB), 256, 0, stream>>>(x, w_qkv, b_qkv, q_ws, k_ws, v_ws);
    denom_kernel<<<dim3(32, BB * HH), 256, 0, stream>>>(q_ws, k_ws, invz);
    attn_kernel<<<dim3(32, BB * HH), 256, 0, stream>>>(q_ws, k_ws, v_ws, invz, attnT);
    out_kernel<<<dim3(8, 8, BB), 256, 0, stream>>>(attnT, x, w_out, b_out,
                                                   bnw, bnb, bnm, bnv, out);
}

// Round 2
// 171.130 us; speedup vs baseline: 4.5228x; 4.5228x over previous
//
#include <hip/hip_runtime.h>
#include <math.h>

#define BB 4
#define CIN 128
#define LL 2048
#define HH 8
#define CH 32
#define HID 256

typedef __attribute__((ext_vector_type(8))) __bf16 bf16x8;
typedef __attribute__((ext_vector_type(4))) float f32x4;

static __device__ __forceinline__ unsigned int f2bf(float f) {
    union { __bf16 b; unsigned short s; } u;
    u.b = (__bf16)f;
    return (unsigned int)u.s;
}

__device__ __forceinline__ float dot4(float4 a, float4 b) {
    return a.x*b.x + a.y*b.y + a.z*b.z + a.w*b.w;
}

// ---------------------------------------------------------------------------
// Kernel 1: QKV 1x1 conv -> bf16 buffers.
// Q: [bh][l][d] bf16, pre-scaled by 1/sqrt(L).  K: [bh][l][d] bf16.
// V: transposed [bh][d][l] bf16 (so PV B-fragments are contiguous).
// ---------------------------------------------------------------------------
__global__ __launch_bounds__(256) void qkv_kernel(
        const float* __restrict__ x, const float* __restrict__ w_qkv,
        const float* __restrict__ b_qkv,
        unsigned short* __restrict__ qb, unsigned short* __restrict__ kb,
        unsigned short* __restrict__ vtb) {
    __shared__ float wl[32 * 128];
    __shared__ float tr[32 * 65];
    const int t = threadIdx.x;
    const int lt = blockIdx.x;           // 0..31
    const int g  = blockIdx.y;           // 0..23 : sel*8 + h
    const int b  = blockIdx.z;
    const int sel = g >> 3, h = g & 7;
    const int obase = sel * 256 + h * 32;
    const int l0 = lt * 64;

    const float4* wsrc = (const float4*)(w_qkv + (size_t)obase * CIN);
    float4* wdst = (float4*)wl;
    #pragma unroll
    for (int r = 0; r < 4; ++r) wdst[r * 256 + t] = wsrc[r * 256 + t];
    __syncthreads();

    const int ll = t & 63, og = t >> 6;
    float acc[8] = {0.f,0.f,0.f,0.f,0.f,0.f,0.f,0.f};
    const float* xp = x + (size_t)b * CIN * LL + l0 + ll;
    for (int i = 0; i < CIN; i += 4) {
        float x0 = xp[(size_t)(i+0) * LL];
        float x1 = xp[(size_t)(i+1) * LL];
        float x2 = xp[(size_t)(i+2) * LL];
        float x3 = xp[(size_t)(i+3) * LL];
        #pragma unroll
        for (int j = 0; j < 8; ++j) {
            float4 w4 = *(const float4*)(wl + (og * 8 + j) * 128 + i);
            acc[j] += w4.x * x0 + w4.y * x1 + w4.z * x2 + w4.w * x3;
        }
    }
    const float scale = (sel == 0) ? 0.02209708691207961f : 1.0f;  // 1/sqrt(2048)
    #pragma unroll
    for (int j = 0; j < 8; ++j) {
        int oc = og * 8 + j;
        tr[oc * 65 + ll] = (acc[j] + b_qkv[obase + oc]) * scale;   // [c][l]
    }
    __syncthreads();
    if (sel == 2) {
        // V^T: [d][l]
        unsigned short* dst = vtb + ((size_t)(b * HH + h) * CH) * LL + l0;
        #pragma unroll
        for (int r = 0; r < 8; ++r) {
            int flat = r * 256 + t;           // c*64 + l
            int c = flat >> 6, l = flat & 63;
            dst[(size_t)c * LL + l] = (unsigned short)f2bf(tr[c * 65 + l]);
        }
    } else {
        unsigned short* dst = (sel == 0 ? qb : kb)
                              + ((size_t)(b * HH + h) * LL + l0) * CH;
        #pragma unroll
        for (int r = 0; r < 8; ++r) {
            int flat = r * 256 + t;           // lr*32 + c
            int c = flat & 31, lr = flat >> 5;
            dst[flat] = (unsigned short)f2bf(tr[c * 65 + lr]);
        }
    }
}

// ---------------------------------------------------------------------------
// Kernel 2: softmax denominators via MFMA.
// invz[bh][q] = 1 / sum_a exp(q . k_a).  Wave owns 16 q rows; loop a.
// A-frag (Q) loop-invariant; B-frag (K) streamed from L2.
// ---------------------------------------------------------------------------
__global__ __launch_bounds__(256) void denom_mfma(
        const unsigned short* __restrict__ qb,
        const unsigned short* __restrict__ kb,
        float* __restrict__ invz) {
    const int t = threadIdx.x, wave = t >> 6, lane = t & 63;
    const int qt = blockIdx.x;   // 0..31 (q-tile of 64)
    const int bh = blockIdx.y;   // 0..31
    const int q0 = qt * 64 + wave * 16;
    const int r = lane & 15, g = lane >> 4;

    bf16x8 afrag = *(const bf16x8*)(qb + ((size_t)bh * LL + q0 + r) * CH + 8 * g);
    const unsigned short* kp = kb + ((size_t)bh * LL + r) * CH + 8 * g;

    float z0 = 0.f, z1 = 0.f, z2 = 0.f, z3 = 0.f;
    const f32x4 zero = {0.f, 0.f, 0.f, 0.f};
    for (int a0 = 0; a0 < LL; a0 += 64) {
        #pragma unroll
        for (int s = 0; s < 4; ++s) {
            bf16x8 bfrag = *(const bf16x8*)(kp + (size_t)(a0 + s * 16) * CH);
            f32x4 d = __builtin_amdgcn_mfma_f32_16x16x32_bf16(afrag, bfrag, zero, 0, 0, 0);
            z0 += __expf(d[0]); z1 += __expf(d[1]);
            z2 += __expf(d[2]); z3 += __expf(d[3]);
        }
    }
    #pragma unroll
    for (int m = 1; m < 16; m <<= 1) {
        z0 += __shfl_xor(z0, m); z1 += __shfl_xor(z1, m);
        z2 += __shfl_xor(z2, m); z3 += __shfl_xor(z3, m);
    }
    if (r == 0) {
        float4 w = make_float4(1.f / z0, 1.f / z1, 1.f / z2, 1.f / z3);
        *(float4*)(invz + (size_t)bh * LL + q0 + 4 * g) = w;   // rows q0+4g..+3
    }
}

// ---------------------------------------------------------------------------
// Kernel 3: attn^T via MFMA.  attnT[b][h*32+d][a] = sum_q P[q,a] V[q,d].
// Wave owns 32 a-cols (2 N-tiles) x d=32 (2 N-tiles of PV). Loop q by 32.
// S-tiles -> exp*invz -> bf16 P^T bounce through per-wave LDS -> PV MFMAs.
// ---------------------------------------------------------------------------
__global__ __launch_bounds__(256) void attn_mfma(
        const unsigned short* __restrict__ qb,
        const unsigned short* __restrict__ kb,
        const unsigned short* __restrict__ vtb,
        const float* __restrict__ invz,
        float* __restrict__ attnT) {
    __shared__ __align__(16) float zl[LL];                 // 8 KB
    __shared__ __align__(16) unsigned short pt[4][32][56]; // per-wave P^T, 14 KB
    const int t = threadIdx.x, wave = t >> 6, lane = t & 63;
    const int bh = blockIdx.y, b = bh >> 3, h = bh & 7;
    const int ab = blockIdx.x * 128 + wave * 32;
    const int r = lane & 15, g = lane >> 4;

    for (int i = t; i < LL / 4; i += 256)
        ((float4*)zl)[i] = ((const float4*)(invz + (size_t)bh * LL))[i];
    __syncthreads();

    const unsigned short* kp = kb + ((size_t)bh * LL + ab + r) * CH + 8 * g;
    bf16x8 kf0 = *(const bf16x8*)kp;                 // a-sub 0
    bf16x8 kf1 = *(const bf16x8*)(kp + 16 * CH);     // a-sub 1

    const unsigned short* qp  = qb  + ((size_t)bh * LL + r) * CH + 8 * g;
    const unsigned short* vp0 = vtb + ((size_t)bh * CH + r) * LL + 8 * g;   // d 0..15
    const unsigned short* vp1 = vp0 + (size_t)16 * LL;                       // d 16..31

    f32x4 acc00 = {0,0,0,0}, acc01 = {0,0,0,0}, acc10 = {0,0,0,0}, acc11 = {0,0,0,0};
    const f32x4 zero = {0.f, 0.f, 0.f, 0.f};

    for (int q0 = 0; q0 < LL; q0 += 32) {
        bf16x8 qf0 = *(const bf16x8*)(qp + (size_t)q0 * CH);
        bf16x8 qf1 = *(const bf16x8*)(qp + (size_t)(q0 + 16) * CH);
        // S tiles: D[q-sub rows][a-sub cols]
        f32x4 s00 = __builtin_amdgcn_mfma_f32_16x16x32_bf16(qf0, kf0, zero, 0, 0, 0);
        f32x4 s01 = __builtin_amdgcn_mfma_f32_16x16x32_bf16(qf0, kf1, zero, 0, 0, 0);
        f32x4 s10 = __builtin_amdgcn_mfma_f32_16x16x32_bf16(qf1, kf0, zero, 0, 0, 0);
        f32x4 s11 = __builtin_amdgcn_mfma_f32_16x16x32_bf16(qf1, kf1, zero, 0, 0, 0);
        float4 iz0 = *(const float4*)(zl + q0 + 4 * g);        // q rows of sub 0
        float4 iz1 = *(const float4*)(zl + q0 + 16 + 4 * g);   // q rows of sub 1
        // P = exp(S)*invz[q]; write P^T[a_local][q_local] as bf16
        {
            unsigned int u0, u1;
            u0 = f2bf(__expf(s00[0]) * iz0.x) | (f2bf(__expf(s00[1]) * iz0.y) << 16);
            u1 = f2bf(__expf(s00[2]) * iz0.z) | (f2bf(__expf(s00[3]) * iz0.w) << 16);
            *(uint2*)&pt[wave][r][4 * g] = make_uint2(u0, u1);        // (qs0,as0)
            u0 = f2bf(__expf(s01[0]) * iz0.x) | (f2bf(__expf(s01[1]) * iz0.y) << 16);
            u1 = f2bf(__expf(s01[2]) * iz0.z) | (f2bf(__expf(s01[3]) * iz0.w) << 16);
            *(uint2*)&pt[wave][16 + r][4 * g] = make_uint2(u0, u1);   // (qs0,as1)
            u0 = f2bf(__expf(s10[0]) * iz1.x) | (f2bf(__expf(s10[1]) * iz1.y) << 16);
            u1 = f2bf(__expf(s10[2]) * iz1.z) | (f2bf(__expf(s10[3]) * iz1.w) << 16);
            *(uint2*)&pt[wave][r][16 + 4 * g] = make_uint2(u0, u1);   // (qs1,as0)
            u0 = f2bf(__expf(s11[0]) * iz1.x) | (f2bf(__expf(s11[1]) * iz1.y) << 16);
            u1 = f2bf(__expf(s11[2]) * iz1.z) | (f2bf(__expf(s11[3]) * iz1.w) << 16);
            *(uint2*)&pt[wave][16 + r][16 + 4 * g] = make_uint2(u0, u1);
        }
        asm volatile("s_waitcnt lgkmcnt(0)" ::: "memory");
        // PV: A = P^T (a x q), B = V (q x d)
        bf16x8 pa0 = *(const bf16x8*)&pt[wave][r][8 * g];
        bf16x8 pa1 = *(const bf16x8*)&pt[wave][16 + r][8 * g];
        bf16x8 vf0 = *(const bf16x8*)(vp0 + q0);
        bf16x8 vf1 = *(const bf16x8*)(vp1 + q0);
        acc00 = __builtin_amdgcn_mfma_f32_16x16x32_bf16(pa0, vf0, acc00, 0, 0, 0);
        acc01 = __builtin_amdgcn_mfma_f32_16x16x32_bf16(pa0, vf1, acc01, 0, 0, 0);
        acc10 = __builtin_amdgcn_mfma_f32_16x16x32_bf16(pa1, vf0, acc10, 0, 0, 0);
        acc11 = __builtin_amdgcn_mfma_f32_16x16x32_bf16(pa1, vf1, acc11, 0, 0, 0);
    }

    float* ob = attnT + ((size_t)b * HID + h * CH) * LL;
    *(f32x4*)(ob + (size_t)(r     ) * LL + ab +      4 * g) = acc00;  // as0, d 0..15
    *(f32x4*)(ob + (size_t)(16 + r) * LL + ab +      4 * g) = acc01;  // as0, d 16..31
    *(f32x4*)(ob + (size_t)(r     ) * LL + ab + 16 + 4 * g) = acc10;  // as1, d 0..15
    *(f32x4*)(ob + (size_t)(16 + r) * LL + ab + 16 + 4 * g) = acc11;  // as1, d 16..31
}

// ---------------------------------------------------------------------------
// Kernel 4: out[b,o,l] = BN( w_out @ attnT + b_out + x )
// ---------------------------------------------------------------------------
__global__ __launch_bounds__(256) void out_kernel(
        const float* __restrict__ attnT, const float* __restrict__ x,
        const float* __restrict__ w_out, const float* __restrict__ b_out,
        const float* __restrict__ bnw, const float* __restrict__ bnb,
        const float* __restrict__ bnm, const float* __restrict__ bnv,
        float* __restrict__ out) {
    __shared__ float wl[16 * 256];
    const int t = threadIdx.x;
    const int l0 = blockIdx.x * 256;
    const int o0 = blockIdx.y * 16;
    const int b  = blockIdx.z;

    const float4* ws = (const float4*)(w_out + (size_t)o0 * HID);
    float4* wd = (float4*)wl;
    #pragma unroll
    for (int r = 0; r < 4; ++r) wd[r * 256 + t] = ws[r * 256 + t];
    __syncthreads();

    float acc[16];
    #pragma unroll
    for (int j = 0; j < 16; ++j) acc[j] = 0.f;
    const float* ap = attnT + (size_t)b * HID * LL + l0 + t;
    for (int i = 0; i < HID; i += 4) {
        float a0 = ap[(size_t)(i+0) * LL];
        float a1 = ap[(size_t)(i+1) * LL];
        float a2 = ap[(size_t)(i+2) * LL];
        float a3 = ap[(size_t)(i+3) * LL];
        #pragma unroll
        for (int j = 0; j < 16; ++j) {
            float4 w4 = *(const float4*)(wl + j * 256 + i);
            acc[j] += w4.x * a0 + w4.y * a1 + w4.z * a2 + w4.w * a3;
        }
    }
    #pragma unroll
    for (int j = 0; j < 16; ++j) {
        const int o = o0 + j;
        const float inv = bnw[o] / sqrtf(bnv[o] + 1e-5f);
        const float sh  = bnb[o] - bnm[o] * inv;
        const size_t idx = ((size_t)b * CIN + o) * LL + l0 + t;
        float val = acc[j] + b_out[o] + x[idx];
        out[idx] = val * inv + sh;
    }
}

// ---------------------------------------------------------------------------
extern "C" void kernel_launch(void* const* d_in, const int* in_sizes, int n_in,
                              void* d_out, int out_size, void* d_ws, size_t ws_size,
                              hipStream_t stream) {
    const float* x      = (const float*)d_in[0];
    const float* w_qkv  = (const float*)d_in[1];
    const float* b_qkv  = (const float*)d_in[2];
    const float* w_out  = (const float*)d_in[3];
    const float* b_out  = (const float*)d_in[4];
    const float* bnw    = (const float*)d_in[5];
    const float* bnb    = (const float*)d_in[6];
    const float* bnm    = (const float*)d_in[7];
    const float* bnv    = (const float*)d_in[8];
    float* out = (float*)d_out;

    const size_t NBH = (size_t)BB * HH;          // 32
    const size_t QKV_ELEMS = NBH * LL * CH;      // 2,097,152 bf16 elems each
    unsigned short* qb  = (unsigned short*)d_ws;
    unsigned short* kb  = qb + QKV_ELEMS;
    unsigned short* vtb = kb + QKV_ELEMS;
    float* invz  = (float*)(vtb + QKV_ELEMS);    // 12 MB offset, 256 KB
    float* attnT = invz + NBH * LL;              // 8 MB

    qkv_kernel<<<dim3(32, 24, BB), 256, 0, stream>>>(x, w_qkv, b_qkv, qb, kb, vtb);
    denom_mfma<<<dim3(32, NBH), 256, 0, stream>>>(qb, kb, invz);
    attn_mfma<<<dim3(16, NBH), 256, 0, stream>>>(qb, kb, vtb, invz, attnT);
    out_kernel<<<dim3(8, 8, BB), 256, 0, stream>>>(attnT, x, w_out, b_out,
                                                   bnw, bnb, bnm, bnv, out);
}